// Round 3
// baseline (126.330 us; speedup 1.0000x reference)
//
#include <hip/hip_runtime.h>
#include <math.h>

#ifndef M_PI
#define M_PI 3.14159265358979323846
#endif

#define LUT_N 4096
#define WPB 4  // waves per block in flash

// nearest-entry LUT cos, replicating jnp round-half-even + float mod semantics
__device__ __forceinline__ float lut_cos(float theta) {
    const float IDX_SCALE = (float)((double)LUT_N / (2.0 * M_PI)); // fl(4096/2pi)
    const float STEP = (float)((2.0 * M_PI) / (double)LUT_N);      // fl(2pi/4096)
    float x = theta * IDX_SCALE;
    int i = (int)rintf(x);     // round-half-even, matches jnp.round/np.round
    i &= (LUT_N - 1);          // == Python mod for pow2 in two's complement
    return cosf((float)i * STEP);
}

__global__ void qgen_kernel(const float* __restrict__ cur_r,
                            const float* __restrict__ cur_i,
                            const float* __restrict__ w_q,
                            const float* __restrict__ b_q,
                            const float* __restrict__ t_ptr,
                            float* __restrict__ q_out,
                            int B, int D) {
    int idx = blockIdx.x * blockDim.x + threadIdx.x;
    int twoD = 2 * D;
    if (idx >= B * twoD) return;
    int b = idx / twoD;
    int c = idx - b * twoD;
    int col = (c < D) ? c : c - D;
    const float* src = (c < D) ? cur_r : cur_i;
    float v = src[(size_t)b * D + col];
    float t_phi = t_ptr[0] * 1.61803398874989484820f;  // f32(PHI), f32 multiply
    float wl = 1.0f + fabsf(w_q[col]);
    float theta = v / wl + b_q[col] + t_phi;           // same op order as ref
    q_out[idx] = lut_cos(theta);
}

// Wave-autonomous flash: one wave owns a FULL 4096-wide key row (16 float4
// per lane). No barriers / no cross-wave traffic in the row loop. Each wave
// processes R = H/S/WPB consecutive rows with a private online softmax
// (defer-max: rescale only when score jumps by >8, wave-uniform branch).
// End-of-kernel: 4-wave LDS merge -> one partial (4096 f32 + M,L) per block.
// Requires 2D == 4096.
__global__ __launch_bounds__(256, 2) void flash_kernel(
    const float* __restrict__ hist_r,
    const float* __restrict__ hist_i,
    const float* __restrict__ q_ws,
    float* __restrict__ r_ws,
    float* __restrict__ ml_ws,
    int H, int S) {
    const int t = threadIdx.x;
    const int lane = t & 63;
    const int wv = t >> 6;                 // 0..3
    const int b = blockIdx.x / S;
    const int s = blockIdx.x - b * S;
    const int rows_blk = H / S;            // e.g. 64
    const int R = rows_blk / WPB;          // rows per wave, e.g. 16
    const int h0 = s * rows_blk + wv * R;

    // 512 float4 per 2048-wide half-row
    const float4* hr = (const float4*)hist_r + ((size_t)b * H + h0) * 512;
    const float4* hi = (const float4*)hist_i + ((size_t)b * H + h0) * 512;
    const float4* q4 = (const float4*)q_ws + (size_t)b * 1024;

    float4 qv[16];
#pragma unroll
    for (int j = 0; j < 16; ++j) qv[j] = q4[j * 64 + lane];

    float4 rv[16];
#pragma unroll
    for (int j = 0; j < 16; ++j) rv[j] = make_float4(0.f, 0.f, 0.f, 0.f);
    float m0 = -INFINITY, l = 0.f;
    const float inv_scale = 1.0f / 64.0f;  // 1/sqrt(2*2048), exact

    for (int r = 0; r < R; ++r) {
        float4 kv[16];
#pragma unroll
        for (int j = 0; j < 8; ++j) kv[j] = hr[(size_t)r * 512 + j * 64 + lane];
#pragma unroll
        for (int j = 0; j < 8; ++j) kv[8 + j] = hi[(size_t)r * 512 + j * 64 + lane];

        float p = 0.f;
#pragma unroll
        for (int j = 0; j < 16; ++j)
            p += qv[j].x * kv[j].x + qv[j].y * kv[j].y +
                 qv[j].z * kv[j].z + qv[j].w * kv[j].w;
#pragma unroll
        for (int off = 32; off; off >>= 1) p += __shfl_xor(p, off);
        float sc = p * inv_scale;          // wave-uniform after xor-reduce

        float d = sc - m0;
        float w;
        if (d > 8.0f) {                    // rare, wave-uniform; first row: d=+inf
            float corr = __expf(-d);       // first row: exp(-inf) = 0
            l *= corr;
#pragma unroll
            for (int j = 0; j < 16; ++j) {
                rv[j].x *= corr; rv[j].y *= corr;
                rv[j].z *= corr; rv[j].w *= corr;
            }
            m0 = sc;
            w = 1.0f;
        } else {
            w = __expf(d);                 // bounded by e^8
        }
        l += w;
#pragma unroll
        for (int j = 0; j < 16; ++j) {
            rv[j].x = fmaf(w, kv[j].x, rv[j].x);
            rv[j].y = fmaf(w, kv[j].y, rv[j].y);
            rv[j].z = fmaf(w, kv[j].z, rv[j].z);
            rv[j].w = fmaf(w, kv[j].w, rv[j].w);
        }
    }

    // ---- end-of-kernel block merge (only barriers in the kernel) ----
    __shared__ float4 sred[1024];          // 16 KB
    __shared__ float sm[WPB], sl[WPB];
    if (lane == 0) { sm[wv] = m0; sl[wv] = l; }
    __syncthreads();
    float M = fmaxf(fmaxf(sm[0], sm[1]), fmaxf(sm[2], sm[3]));
    float Lb = sl[0] * __expf(sm[0] - M) + sl[1] * __expf(sm[1] - M) +
               sl[2] * __expf(sm[2] - M) + sl[3] * __expf(sm[3] - M);
    float scale = __expf(m0 - M);          // per-wave rescale to block max

    for (int w = 0; w < WPB; ++w) {
        if (wv == w) {
#pragma unroll
            for (int j = 0; j < 16; ++j) {
                int idx = j * 64 + lane;
                float4 v = (w == 0) ? make_float4(0.f, 0.f, 0.f, 0.f) : sred[idx];
                v.x = fmaf(scale, rv[j].x, v.x);
                v.y = fmaf(scale, rv[j].y, v.y);
                v.z = fmaf(scale, rv[j].z, v.z);
                v.w = fmaf(scale, rv[j].w, v.w);
                sred[idx] = v;
            }
        }
        __syncthreads();
    }

    float4* ro = (float4*)r_ws + (size_t)blockIdx.x * 1024;
#pragma unroll
    for (int k = 0; k < 4; ++k) ro[t + 256 * k] = sred[t + 256 * k];
    if (t == 0) {
        ml_ws[2 * (size_t)blockIdx.x] = M;
        ml_ws[2 * (size_t)blockIdx.x + 1] = Lb;
    }
}

// grid = B * (2D/256) blocks; each thread owns one output column.
__global__ void combine_kernel(const float* __restrict__ r_ws,
                               const float* __restrict__ ml_ws,
                               const float* __restrict__ ema,
                               const float* __restrict__ alpha_ptr,
                               float* __restrict__ out,
                               int D, int S) {
    const int twoD = 2 * D;
    const int nc = twoD / 256;
    const int b = blockIdx.x / nc;
    const int cb = blockIdx.x - b * nc;
    const int c = cb * 256 + threadIdx.x;

    const float* ml = ml_ws + (size_t)b * S * 2;
    float M = -INFINITY;
    for (int s = 0; s < S; ++s) M = fmaxf(M, ml[2 * s]);
    float L = 0.f;
    for (int s = 0; s < S; ++s) L += ml[2 * s + 1] * __expf(ml[2 * s] - M);

    float acc = 0.f;
    const float* rb = r_ws + (size_t)b * S * twoD + c;
    for (int s = 0; s < S; ++s)
        acc = fmaf(__expf(ml[2 * s] - M), rb[(size_t)s * twoD], acc);

    float a = 1.0f / (1.0f + __expf(-alpha_ptr[0]));  // sigmoid(alpha)
    float retrieved = acc / L;
    size_t o = (size_t)b * twoD + c;
    out[o] = a * retrieved + (1.0f - a) * ema[o];
}

extern "C" void kernel_launch(void* const* d_in, const int* in_sizes, int n_in,
                              void* d_out, int out_size, void* d_ws, size_t ws_size,
                              hipStream_t stream) {
    const float* cur_r  = (const float*)d_in[0];
    const float* cur_i  = (const float*)d_in[1];
    const float* hist_r = (const float*)d_in[2];
    const float* hist_i = (const float*)d_in[3];
    const float* ema    = (const float*)d_in[4];
    const float* w_q    = (const float*)d_in[5];
    const float* b_q    = (const float*)d_in[6];
    const float* alpha  = (const float*)d_in[7];
    const float* t      = (const float*)d_in[8];

    const int D = in_sizes[5];                 // 2048
    const int B = in_sizes[0] / D;             // 16
    const int H = in_sizes[2] / (B * D);       // 2048
    const int twoD = 2 * D;

    float* q_ws = (float*)d_ws;
    size_t q_elems = (size_t)B * twoD;

    int S = 32;  // 512 blocks x 256 thr = 2 blocks/CU; rows/wave = H/S/WPB = 16
    while (S > 1) {
        size_t need = (q_elems + (size_t)B * S * twoD + (size_t)B * S * 2) * sizeof(float);
        if (need <= ws_size) break;
        S >>= 1;
    }
    float* r_ws = q_ws + q_elems;
    float* ml_ws = r_ws + (size_t)B * S * twoD;

    int qblocks = (B * twoD + 255) / 256;
    qgen_kernel<<<qblocks, 256, 0, stream>>>(cur_r, cur_i, w_q, b_q, t, q_ws, B, D);
    flash_kernel<<<B * S, 256, 0, stream>>>(hist_r, hist_i, q_ws, r_ws, ml_ws, H, S);
    combine_kernel<<<B * (twoD / 256), 256, 0, stream>>>(r_ws, ml_ws, ema, alpha,
                                                         (float*)d_out, D, S);
}

// Round 4
// 123.342 us; speedup vs baseline: 1.0242x; 1.0242x over previous
//
#include <hip/hip_runtime.h>
#include <math.h>

#ifndef M_PI
#define M_PI 3.14159265358979323846
#endif

#define LUT_N 4096
#define WPB 4  // waves per block in flash

// nearest-entry LUT cos, replicating jnp round-half-even + float mod semantics
__device__ __forceinline__ float lut_cos(float theta) {
    const float IDX_SCALE = (float)((double)LUT_N / (2.0 * M_PI)); // fl(4096/2pi)
    const float STEP = (float)((2.0 * M_PI) / (double)LUT_N);      // fl(2pi/4096)
    float x = theta * IDX_SCALE;
    int i = (int)rintf(x);     // round-half-even, matches jnp.round/np.round
    i &= (LUT_N - 1);          // == Python mod for pow2 in two's complement
    return cosf((float)i * STEP);
}

__global__ void qgen_kernel(const float* __restrict__ cur_r,
                            const float* __restrict__ cur_i,
                            const float* __restrict__ w_q,
                            const float* __restrict__ b_q,
                            const float* __restrict__ t_ptr,
                            float* __restrict__ q_out,
                            int B, int D) {
    int idx = blockIdx.x * blockDim.x + threadIdx.x;
    int twoD = 2 * D;
    if (idx >= B * twoD) return;
    int b = idx / twoD;
    int c = idx - b * twoD;
    int col = (c < D) ? c : c - D;
    const float* src = (c < D) ? cur_r : cur_i;
    float v = src[(size_t)b * D + col];
    float t_phi = t_ptr[0] * 1.61803398874989484820f;  // f32(PHI), f32 multiply
    float wl = 1.0f + fabsf(w_q[col]);
    float theta = v / wl + b_q[col] + t_phi;           // same op order as ref
    q_out[idx] = lut_cos(theta);
}

// Wave-autonomous flash: one wave owns a FULL 4096-wide key row (16 float4
// per lane). q lives in LDS (shared by the block's 4 waves -> frees 64 VGPRs
// so kv[16] loads issue 16-deep with one vmcnt wait). rv accumulator stays in
// registers. No barriers in the row loop. Defer-max online softmax.
// End-of-kernel: 4-wave LDS merge -> one partial (4096 f32 + M,L) per block.
// Requires 2D == 4096.
__global__ __launch_bounds__(256, 2) void flash_kernel(
    const float* __restrict__ hist_r,
    const float* __restrict__ hist_i,
    const float* __restrict__ q_ws,
    float* __restrict__ r_ws,
    float* __restrict__ ml_ws,
    int H, int S) {
    const int t = threadIdx.x;
    const int lane = t & 63;
    const int wv = t >> 6;                 // 0..3
    const int b = blockIdx.x / S;
    const int s = blockIdx.x - b * S;
    const int rows_blk = H / S;            // e.g. 64
    const int R = rows_blk / WPB;          // rows per wave, e.g. 16
    const int h0 = s * rows_blk + wv * R;

    __shared__ float4 qsh[1024];           // 16 KB: the block's query (batch b)
    __shared__ float4 sred[1024];          // 16 KB: end-of-kernel merge
    __shared__ float sm[WPB], sl[WPB];

    const float4* q4 = (const float4*)q_ws + (size_t)b * 1024;
#pragma unroll
    for (int k = 0; k < 4; ++k) qsh[t + 256 * k] = q4[t + 256 * k];
    __syncthreads();

    // 512 float4 per 2048-wide half-row
    const float4* hr = (const float4*)hist_r + ((size_t)b * H + h0) * 512 + lane;
    const float4* hi = (const float4*)hist_i + ((size_t)b * H + h0) * 512 + lane;

    float4 rv[16];
#pragma unroll
    for (int j = 0; j < 16; ++j) rv[j] = make_float4(0.f, 0.f, 0.f, 0.f);
    float m0 = -INFINITY, l = 0.f;
    const float inv_scale = 1.0f / 64.0f;  // 1/sqrt(2*2048), exact

    for (int r = 0; r < R; ++r) {
        // stop LICM from hoisting the (loop-invariant) LDS q reads back into
        // 64 registers; everything inside one iteration schedules freely
        asm volatile("" ::: "memory");

        float4 kv[16];
#pragma unroll
        for (int j = 0; j < 8; ++j) kv[j] = hr[(size_t)r * 512 + j * 64];
#pragma unroll
        for (int j = 0; j < 8; ++j) kv[8 + j] = hi[(size_t)r * 512 + j * 64];

        float p = 0.f;
#pragma unroll
        for (int j = 0; j < 16; ++j) {
            float4 qv = qsh[j * 64 + lane];
            p += qv.x * kv[j].x + qv.y * kv[j].y +
                 qv.z * kv[j].z + qv.w * kv[j].w;
        }
#pragma unroll
        for (int off = 32; off; off >>= 1) p += __shfl_xor(p, off);
        float sc = p * inv_scale;          // wave-uniform after xor-reduce

        float d = sc - m0;
        float w;
        if (d > 8.0f) {                    // rare, wave-uniform; first row: d=+inf
            float corr = __expf(-d);       // first row: exp(-inf) = 0
            l *= corr;
#pragma unroll
            for (int j = 0; j < 16; ++j) {
                rv[j].x *= corr; rv[j].y *= corr;
                rv[j].z *= corr; rv[j].w *= corr;
            }
            m0 = sc;
            w = 1.0f;
        } else {
            w = __expf(d);                 // bounded by e^8
        }
        l += w;
#pragma unroll
        for (int j = 0; j < 16; ++j) {
            rv[j].x = fmaf(w, kv[j].x, rv[j].x);
            rv[j].y = fmaf(w, kv[j].y, rv[j].y);
            rv[j].z = fmaf(w, kv[j].z, rv[j].z);
            rv[j].w = fmaf(w, kv[j].w, rv[j].w);
        }
    }

    // ---- end-of-kernel block merge (only barriers in the kernel) ----
    if (lane == 0) { sm[wv] = m0; sl[wv] = l; }
    __syncthreads();
    float M = fmaxf(fmaxf(sm[0], sm[1]), fmaxf(sm[2], sm[3]));
    float Lb = sl[0] * __expf(sm[0] - M) + sl[1] * __expf(sm[1] - M) +
               sl[2] * __expf(sm[2] - M) + sl[3] * __expf(sm[3] - M);
    float scale = __expf(m0 - M);          // per-wave rescale to block max

    for (int w = 0; w < WPB; ++w) {
        if (wv == w) {
#pragma unroll
            for (int j = 0; j < 16; ++j) {
                int idx = j * 64 + lane;
                float4 v = (w == 0) ? make_float4(0.f, 0.f, 0.f, 0.f) : sred[idx];
                v.x = fmaf(scale, rv[j].x, v.x);
                v.y = fmaf(scale, rv[j].y, v.y);
                v.z = fmaf(scale, rv[j].z, v.z);
                v.w = fmaf(scale, rv[j].w, v.w);
                sred[idx] = v;
            }
        }
        __syncthreads();
    }

    float4* ro = (float4*)r_ws + (size_t)blockIdx.x * 1024;
#pragma unroll
    for (int k = 0; k < 4; ++k) ro[t + 256 * k] = sred[t + 256 * k];
    if (t == 0) {
        ml_ws[2 * (size_t)blockIdx.x] = M;
        ml_ws[2 * (size_t)blockIdx.x + 1] = Lb;
    }
}

// grid = B * (2D/256) blocks; each thread owns one output column.
__global__ void combine_kernel(const float* __restrict__ r_ws,
                               const float* __restrict__ ml_ws,
                               const float* __restrict__ ema,
                               const float* __restrict__ alpha_ptr,
                               float* __restrict__ out,
                               int D, int S) {
    const int twoD = 2 * D;
    const int nc = twoD / 256;
    const int b = blockIdx.x / nc;
    const int cb = blockIdx.x - b * nc;
    const int c = cb * 256 + threadIdx.x;

    const float* ml = ml_ws + (size_t)b * S * 2;
    float M = -INFINITY;
    for (int s = 0; s < S; ++s) M = fmaxf(M, ml[2 * s]);
    float L = 0.f;
    for (int s = 0; s < S; ++s) L += ml[2 * s + 1] * __expf(ml[2 * s] - M);

    float acc = 0.f;
    const float* rb = r_ws + (size_t)b * S * twoD + c;
    for (int s = 0; s < S; ++s)
        acc = fmaf(__expf(ml[2 * s] - M), rb[(size_t)s * twoD], acc);

    float a = 1.0f / (1.0f + __expf(-alpha_ptr[0]));  // sigmoid(alpha)
    float retrieved = acc / L;
    size_t o = (size_t)b * twoD + c;
    out[o] = a * retrieved + (1.0f - a) * ema[o];
}

extern "C" void kernel_launch(void* const* d_in, const int* in_sizes, int n_in,
                              void* d_out, int out_size, void* d_ws, size_t ws_size,
                              hipStream_t stream) {
    const float* cur_r  = (const float*)d_in[0];
    const float* cur_i  = (const float*)d_in[1];
    const float* hist_r = (const float*)d_in[2];
    const float* hist_i = (const float*)d_in[3];
    const float* ema    = (const float*)d_in[4];
    const float* w_q    = (const float*)d_in[5];
    const float* b_q    = (const float*)d_in[6];
    const float* alpha  = (const float*)d_in[7];
    const float* t      = (const float*)d_in[8];

    const int D = in_sizes[5];                 // 2048
    const int B = in_sizes[0] / D;             // 16
    const int H = in_sizes[2] / (B * D);       // 2048
    const int twoD = 2 * D;

    float* q_ws = (float*)d_ws;
    size_t q_elems = (size_t)B * twoD;

    int S = 32;  // 512 blocks x 256 thr = 2 blocks/CU; rows/wave = H/S/WPB = 16
    while (S > 1) {
        size_t need = (q_elems + (size_t)B * S * twoD + (size_t)B * S * 2) * sizeof(float);
        if (need <= ws_size) break;
        S >>= 1;
    }
    float* r_ws = q_ws + q_elems;
    float* ml_ws = r_ws + (size_t)B * S * twoD;

    int qblocks = (B * twoD + 255) / 256;
    qgen_kernel<<<qblocks, 256, 0, stream>>>(cur_r, cur_i, w_q, b_q, t, q_ws, B, D);
    flash_kernel<<<B * S, 256, 0, stream>>>(hist_r, hist_i, q_ws, r_ws, ml_ws, H, S);
    combine_kernel<<<B * (twoD / 256), 256, 0, stream>>>(r_ws, ml_ws, ema, alpha,
                                                         (float*)d_out, D, S);
}